// Round 1
// baseline (140.180 us; speedup 1.0000x reference)
//
#include <hip/hip_runtime.h>

#define N_   32
#define NC_  4
#define HW_  131072
#define REG_ 0.001

// Kernel 1: partial moment sums.
// grid: (B chunks, N_), block: 256 threads.
// Each block processes chunk of HW_/B h-indices for ALL 4 channels of its n,
// so grid[] is read once. Accumulates 8 moments per channel:
//   k=0..4: sum w^2 * y^k ;  k=5..7: sum w^2 * x * y^(k-5)
// Writes 32 partial sums per block to ws[(n*B+b)*32 + c*8 + k].
__global__ __launch_bounds__(256) void wls_partial(const float* __restrict__ W,
                                                   const float* __restrict__ g,
                                                   float* __restrict__ ws,
                                                   int B) {
    const int n = blockIdx.y;
    const int b = blockIdx.x;
    const int t = threadIdx.x;
    const int chunk = HW_ / B;            // h elements per block
    const int iters = chunk / (256 * 4);  // float4 groups per thread
    const long hbase = (long)b * chunk;

    float acc[NC_][8];
#pragma unroll
    for (int c = 0; c < NC_; ++c)
#pragma unroll
        for (int k = 0; k < 8; ++k) acc[c][k] = 0.f;

    const float4* gvec = (const float4*)g + ((long)n * HW_) / 2;  // 1 float4 = 2 h's

    for (int i = 0; i < iters; ++i) {
        const long h4 = hbase + ((long)i * 256 + t) * 4;  // 4 h's per iter
        const float4 g0 = gvec[h4 / 2];
        const float4 g1 = gvec[h4 / 2 + 1];
        float4 w4[NC_];
#pragma unroll
        for (int c = 0; c < NC_; ++c)
            w4[c] = *(const float4*)(W + ((long)(n * NC_ + c) * HW_ + h4));

        const float xs[4] = {g0.x, g0.z, g1.x, g1.z};
        const float ys[4] = {1.f - g0.y, 1.f - g0.w, 1.f - g1.y, 1.f - g1.w};

#pragma unroll
        for (int j = 0; j < 4; ++j) {
            const float x = xs[j], y = ys[j];
            const float y2 = y * y;
            const float y3 = y2 * y;
            const float y4 = y2 * y2;
#pragma unroll
            for (int c = 0; c < NC_; ++c) {
                const float w  = ((const float*)&w4[c])[j];  // j is compile-time (unrolled)
                const float w2 = w * w;
                const float w2x = w2 * x;
                acc[c][0] += w2;
                acc[c][1] = fmaf(w2, y,  acc[c][1]);
                acc[c][2] = fmaf(w2, y2, acc[c][2]);
                acc[c][3] = fmaf(w2, y3, acc[c][3]);
                acc[c][4] = fmaf(w2, y4, acc[c][4]);
                acc[c][5] += w2x;
                acc[c][6] = fmaf(w2x, y,  acc[c][6]);
                acc[c][7] = fmaf(w2x, y2, acc[c][7]);
            }
        }
    }

    // Wave (64-lane) shuffle reduction for each of the 32 accumulators.
#pragma unroll
    for (int c = 0; c < NC_; ++c)
#pragma unroll
        for (int k = 0; k < 8; ++k) {
            float v = acc[c][k];
#pragma unroll
            for (int off = 32; off >= 1; off >>= 1) v += __shfl_down(v, off, 64);
            acc[c][k] = v;
        }

    __shared__ float lds[4 * 32];  // 4 waves x 32 values
    const int wave = t >> 6, lane = t & 63;
    if (lane == 0) {
#pragma unroll
        for (int c = 0; c < NC_; ++c)
#pragma unroll
            for (int k = 0; k < 8; ++k) lds[wave * 32 + c * 8 + k] = acc[c][k];
    }
    __syncthreads();
    if (t < 32) {
        const float v = lds[t] + lds[32 + t] + lds[64 + t] + lds[96 + t];
        ws[((long)(n * B + b)) * 32 + t] = v;
    }
}

// Kernel 2: final fp64 reduction over B partials + 3x3 Cramer solve per (n,c).
__global__ void wls_solve(const float* __restrict__ ws, float* __restrict__ out, int B) {
    const int tid = blockIdx.x * blockDim.x + threadIdx.x;
    if (tid >= N_ * NC_) return;
    const int n = tid >> 2, c = tid & 3;

    double m[8] = {0, 0, 0, 0, 0, 0, 0, 0};
    for (int b = 0; b < B; ++b) {
        const float* p = ws + ((long)(n * B + b)) * 32 + c * 8;
#pragma unroll
        for (int k = 0; k < 8; ++k) m[k] += (double)p[k];
    }

    // Z (symmetric) and X.  Y = [y^2, y, 1] so Z[p][q] = m_{(2-p)+(2-q)}.
    const double Z00 = m[4] + REG_, Z01 = m[3], Z02 = m[2];
    const double Z11 = m[2] + REG_, Z12 = m[1];
    const double Z22 = m[0] + REG_;
    const double X0 = m[7], X1 = m[6], X2 = m[5];

    const double c00 = Z11 * Z22 - Z12 * Z12;
    const double c01 = Z01 * Z22 - Z12 * Z02;
    const double c02 = Z01 * Z12 - Z11 * Z02;
    const double det = Z00 * c00 - Z01 * c01 + Z02 * c02;
    const double inv = 1.0 / det;

    const double d0 = X0 * (Z11 * Z22 - Z12 * Z12)
                    - Z01 * (X1 * Z22 - Z12 * X2)
                    + Z02 * (X1 * Z12 - Z11 * X2);
    const double d1 = Z00 * (X1 * Z22 - Z12 * X2)
                    - X0 * (Z01 * Z22 - Z12 * Z02)
                    + Z02 * (Z01 * X2 - X1 * Z02);
    const double d2 = Z00 * (Z11 * X2 - X1 * Z12)
                    - Z01 * (Z01 * X2 - X1 * Z02)
                    + X0 * (Z01 * Z12 - Z11 * Z02);

    // Output layout: tuple (beta[:,0], beta[:,1], beta[:,2], beta[:,3]),
    // each (N,3,1) -> out[c*96 + n*3 + p]
    float* o = out + c * (N_ * 3) + n * 3;
    o[0] = (float)(d0 * inv);
    o[1] = (float)(d1 * inv);
    o[2] = (float)(d2 * inv);
}

extern "C" void kernel_launch(void* const* d_in, const int* in_sizes, int n_in,
                              void* d_out, int out_size, void* d_ws, size_t ws_size,
                              hipStream_t stream) {
    const float* W = (const float*)d_in[0];
    const float* g = (const float*)d_in[1];
    float* out = (float*)d_out;
    float* ws  = (float*)d_ws;

    int B = 64;  // chunks per n -> 2048 blocks total, 8 h per thread
    while (B > 1 && (size_t)N_ * B * 32 * sizeof(float) > ws_size) B >>= 1;

    dim3 grid1(B, N_);
    wls_partial<<<grid1, 256, 0, stream>>>(W, g, ws, B);
    wls_solve<<<1, 128, 0, stream>>>(ws, out, B);
}

// Round 2
// 119.453 us; speedup vs baseline: 1.1735x; 1.1735x over previous
//
#include <hip/hip_runtime.h>

#define N_   32
#define NC_  4
#define HW_  131072
#define REG_ 0.001
#define B_   64          // h-chunks per n  -> 2048 blocks
#define CHUNK_ (HW_ / B_)        // 2048 h per block
#define ITERS_ (CHUNK_ / (256 * 4))  // = 2 float4-groups per thread

// Kernel 1: partial moment sums.  grid (B_, N_), 256 threads.
// Each block covers all NC_=4 channels of its (n, h-chunk) so grid[] is read
// once.  8 moments per channel: k=0..4: sum w^2*y^k ; k=5..7: sum w^2*x*y^(k-5).
// All global loads are issued before any compute (MLP).
__global__ __launch_bounds__(256) void wls_partial(const float* __restrict__ W,
                                                   const float* __restrict__ g,
                                                   float* __restrict__ ws) {
    const int n = blockIdx.y;
    const int b = blockIdx.x;
    const int t = threadIdx.x;
    const long hbase = (long)b * CHUNK_;

    const float4* gvec = (const float4*)g + ((long)n * HW_) / 2;  // float4 = 2 h

    // ---- load phase: 2 iters x (2 grid float4 + 4 W float4) = 12 loads ----
    float4 gld[ITERS_][2];
    float4 wld[ITERS_][NC_];
#pragma unroll
    for (int i = 0; i < ITERS_; ++i) {
        const long h4 = hbase + ((long)i * 256 + t) * 4;  // 4 h's
        gld[i][0] = gvec[h4 / 2];
        gld[i][1] = gvec[h4 / 2 + 1];
#pragma unroll
        for (int c = 0; c < NC_; ++c)
            wld[i][c] = *(const float4*)(W + ((long)(n * NC_ + c) * HW_ + h4));
    }

    // ---- compute phase ----
    float acc[NC_][8];
#pragma unroll
    for (int c = 0; c < NC_; ++c)
#pragma unroll
        for (int k = 0; k < 8; ++k) acc[c][k] = 0.f;

#pragma unroll
    for (int i = 0; i < ITERS_; ++i) {
        const float xs[4] = {gld[i][0].x, gld[i][0].z, gld[i][1].x, gld[i][1].z};
        const float ys[4] = {1.f - gld[i][0].y, 1.f - gld[i][0].w,
                             1.f - gld[i][1].y, 1.f - gld[i][1].w};
#pragma unroll
        for (int j = 0; j < 4; ++j) {
            const float x = xs[j], y = ys[j];
            const float y2 = y * y, y3 = y2 * y, y4 = y2 * y2;
#pragma unroll
            for (int c = 0; c < NC_; ++c) {
                const float w  = ((const float*)&wld[i][c])[j];  // unrolled -> const idx
                const float w2 = w * w;
                const float w2x = w2 * x;
                acc[c][0] += w2;
                acc[c][1] = fmaf(w2, y,  acc[c][1]);
                acc[c][2] = fmaf(w2, y2, acc[c][2]);
                acc[c][3] = fmaf(w2, y3, acc[c][3]);
                acc[c][4] = fmaf(w2, y4, acc[c][4]);
                acc[c][5] += w2x;
                acc[c][6] = fmaf(w2x, y,  acc[c][6]);
                acc[c][7] = fmaf(w2x, y2, acc[c][7]);
            }
        }
    }

    // ---- wave (64-lane) shuffle reduction, then cross-wave via LDS ----
#pragma unroll
    for (int c = 0; c < NC_; ++c)
#pragma unroll
        for (int k = 0; k < 8; ++k) {
            float v = acc[c][k];
#pragma unroll
            for (int off = 32; off >= 1; off >>= 1) v += __shfl_down(v, off, 64);
            acc[c][k] = v;
        }

    __shared__ float lds[4 * 32];
    const int wave = t >> 6, lane = t & 63;
    if (lane == 0) {
#pragma unroll
        for (int c = 0; c < NC_; ++c)
#pragma unroll
            for (int k = 0; k < 8; ++k) lds[wave * 32 + c * 8 + k] = acc[c][k];
    }
    __syncthreads();
    if (t < 32)
        ws[((long)(n * B_ + b)) * 32 + t] =
            lds[t] + lds[32 + t] + lds[64 + t] + lds[96 + t];
}

// Kernel 2: 128 blocks (one per (n,c)) x 64 lanes.  Lane b loads partial b's
// 8 moments (two float4), fp64 butterfly reduce, lane 0 solves 3x3 (Cramer).
__global__ __launch_bounds__(64) void wls_solve(const float* __restrict__ ws,
                                                float* __restrict__ out) {
    const int n = blockIdx.x >> 2, c = blockIdx.x & 3;
    const int lane = threadIdx.x;

    const float4* p = (const float4*)(ws + ((long)(n * B_ + lane)) * 32 + c * 8);
    const float4 a = p[0], b4 = p[1];
    double m[8] = {a.x, a.y, a.z, a.w, b4.x, b4.y, b4.z, b4.w};

#pragma unroll
    for (int off = 32; off >= 1; off >>= 1)
#pragma unroll
        for (int k = 0; k < 8; ++k) m[k] += __shfl_down(m[k], off, 64);

    if (lane == 0) {
        const double Z00 = m[4] + REG_, Z01 = m[3], Z02 = m[2];
        const double Z11 = m[2] + REG_, Z12 = m[1];
        const double Z22 = m[0] + REG_;
        const double X0 = m[7], X1 = m[6], X2 = m[5];

        const double c00 = Z11 * Z22 - Z12 * Z12;
        const double c01 = Z01 * Z22 - Z12 * Z02;
        const double c02 = Z01 * Z12 - Z11 * Z02;
        const double det = Z00 * c00 - Z01 * c01 + Z02 * c02;
        const double inv = 1.0 / det;

        const double d0 = X0 * c00
                        - Z01 * (X1 * Z22 - Z12 * X2)
                        + Z02 * (X1 * Z12 - Z11 * X2);
        const double d1 = Z00 * (X1 * Z22 - Z12 * X2)
                        - X0 * c01
                        + Z02 * (Z01 * X2 - X1 * Z02);
        const double d2 = Z00 * (Z11 * X2 - X1 * Z12)
                        - Z01 * (Z01 * X2 - X1 * Z02)
                        + X0 * c02;

        // out[c*96 + n*3 + p]  (tuple of per-channel (N,3,1) arrays)
        float* o = out + c * (N_ * 3) + n * 3;
        o[0] = (float)(d0 * inv);
        o[1] = (float)(d1 * inv);
        o[2] = (float)(d2 * inv);
    }
}

extern "C" void kernel_launch(void* const* d_in, const int* in_sizes, int n_in,
                              void* d_out, int out_size, void* d_ws, size_t ws_size,
                              hipStream_t stream) {
    const float* W = (const float*)d_in[0];
    const float* g = (const float*)d_in[1];

    dim3 grid1(B_, N_);
    wls_partial<<<grid1, 256, 0, stream>>>(W, g, (float*)d_ws);
    wls_solve<<<N_ * NC_, 64, 0, stream>>>((const float*)d_ws, (float*)d_out);
}

// Round 3
// 118.216 us; speedup vs baseline: 1.1858x; 1.0105x over previous
//
#include <hip/hip_runtime.h>

#define N_   32
#define NC_  4
#define HW_  131072
#define REG_ 0.001
#define B_   16                       // h-chunks per n -> 512 blocks (2/CU)
#define CHUNK_ (HW_ / B_)             // 8192 h per block
#define ITERS_ (CHUNK_ / (256 * 4))   // 8 float4-groups per thread

// Kernel 1: partial moment sums.  grid (B_, N_), 256 threads.
// Each block covers all NC_=4 channels of its (n, h-chunk) so grid[] is read
// once.  8 moments per channel: k=0..4: sum w^2*y^k ; k=5..7: sum w^2*x*y^(k-5).
// 2-stage register pipeline (fully unrolled -> compile-time buffer indices).
__global__ __launch_bounds__(256) void wls_partial(const float* __restrict__ W,
                                                   const float* __restrict__ g,
                                                   float* __restrict__ ws) {
    const int n = blockIdx.y;
    const int b = blockIdx.x;
    const int t = threadIdx.x;
    const int hbase = b * CHUNK_;     // all offsets fit in 32-bit

    const float4* __restrict__ gvec = (const float4*)g + (n * HW_) / 2;

    float4 bg[2][2], bw[2][NC_];

    // prologue: load iter 0
    {
        const int h4 = hbase + t * 4;
        bg[0][0] = gvec[h4 >> 1];
        bg[0][1] = gvec[(h4 >> 1) + 1];
#pragma unroll
        for (int c = 0; c < NC_; ++c)
            bw[0][c] = *(const float4*)(W + (n * NC_ + c) * HW_ + h4);
    }

    float acc[NC_][8];
#pragma unroll
    for (int c = 0; c < NC_; ++c)
#pragma unroll
        for (int k = 0; k < 8; ++k) acc[c][k] = 0.f;

#pragma unroll
    for (int i = 0; i < ITERS_; ++i) {
        const int cur = i & 1, nxt = cur ^ 1;   // compile-time (unrolled)
        if (i + 1 < ITERS_) {
            const int h4 = hbase + ((i + 1) * 256 + t) * 4;
            bg[nxt][0] = gvec[h4 >> 1];
            bg[nxt][1] = gvec[(h4 >> 1) + 1];
#pragma unroll
            for (int c = 0; c < NC_; ++c)
                bw[nxt][c] = *(const float4*)(W + (n * NC_ + c) * HW_ + h4);
        }

        const float xs[4] = {bg[cur][0].x, bg[cur][0].z, bg[cur][1].x, bg[cur][1].z};
        const float ys[4] = {1.f - bg[cur][0].y, 1.f - bg[cur][0].w,
                             1.f - bg[cur][1].y, 1.f - bg[cur][1].w};
#pragma unroll
        for (int j = 0; j < 4; ++j) {
            const float x = xs[j], y = ys[j];
            const float y2 = y * y, y3 = y2 * y, y4 = y2 * y2;
#pragma unroll
            for (int c = 0; c < NC_; ++c) {
                const float w   = ((const float*)&bw[cur][c])[j];  // const idx (unrolled)
                const float w2  = w * w;
                const float w2x = w2 * x;
                acc[c][0] += w2;
                acc[c][1] = fmaf(w2, y,  acc[c][1]);
                acc[c][2] = fmaf(w2, y2, acc[c][2]);
                acc[c][3] = fmaf(w2, y3, acc[c][3]);
                acc[c][4] = fmaf(w2, y4, acc[c][4]);
                acc[c][5] += w2x;
                acc[c][6] = fmaf(w2x, y,  acc[c][6]);
                acc[c][7] = fmaf(w2x, y2, acc[c][7]);
            }
        }
    }

    // ---- wave (64-lane) shuffle reduction, then cross-wave via LDS ----
#pragma unroll
    for (int c = 0; c < NC_; ++c)
#pragma unroll
        for (int k = 0; k < 8; ++k) {
            float v = acc[c][k];
#pragma unroll
            for (int off = 32; off >= 1; off >>= 1) v += __shfl_down(v, off, 64);
            acc[c][k] = v;
        }

    __shared__ float lds[4 * 32];
    const int wave = t >> 6, lane = t & 63;
    if (lane == 0) {
#pragma unroll
        for (int c = 0; c < NC_; ++c)
#pragma unroll
            for (int k = 0; k < 8; ++k) lds[wave * 32 + c * 8 + k] = acc[c][k];
    }
    __syncthreads();
    if (t < 32)
        ws[(n * B_ + b) * 32 + t] =
            lds[t] + lds[32 + t] + lds[64 + t] + lds[96 + t];
}

// Kernel 2: 128 blocks (one per (n,c)) x 64 lanes.  Lanes 0..15 each load one
// partial's 8 moments (two float4), width-16 fp64 shuffle reduce, lane 0 does
// the 3x3 Cramer solve.
__global__ __launch_bounds__(64) void wls_solve(const float* __restrict__ ws,
                                                float* __restrict__ out) {
    const int n = blockIdx.x >> 2, c = blockIdx.x & 3;
    const int lane = threadIdx.x;

    double m[8] = {0, 0, 0, 0, 0, 0, 0, 0};
    if (lane < B_) {
        const float4* p = (const float4*)(ws + (n * B_ + lane) * 32 + c * 8);
        const float4 a = p[0], b4 = p[1];
        m[0] = a.x;  m[1] = a.y;  m[2] = a.z;  m[3] = a.w;
        m[4] = b4.x; m[5] = b4.y; m[6] = b4.z; m[7] = b4.w;
    }

#pragma unroll
    for (int off = 8; off >= 1; off >>= 1)
#pragma unroll
        for (int k = 0; k < 8; ++k) m[k] += __shfl_down(m[k], off, 16);

    if (lane == 0) {
        const double Z00 = m[4] + REG_, Z01 = m[3], Z02 = m[2];
        const double Z11 = m[2] + REG_, Z12 = m[1];
        const double Z22 = m[0] + REG_;
        const double X0 = m[7], X1 = m[6], X2 = m[5];

        const double c00 = Z11 * Z22 - Z12 * Z12;
        const double c01 = Z01 * Z22 - Z12 * Z02;
        const double c02 = Z01 * Z12 - Z11 * Z02;
        const double det = Z00 * c00 - Z01 * c01 + Z02 * c02;
        const double inv = 1.0 / det;

        const double d0 = X0 * c00
                        - Z01 * (X1 * Z22 - Z12 * X2)
                        + Z02 * (X1 * Z12 - Z11 * X2);
        const double d1 = Z00 * (X1 * Z22 - Z12 * X2)
                        - X0 * c01
                        + Z02 * (Z01 * X2 - X1 * Z02);
        const double d2 = Z00 * (Z11 * X2 - X1 * Z12)
                        - Z01 * (Z01 * X2 - X1 * Z02)
                        + X0 * c02;

        // out[c*96 + n*3 + p]  (tuple of per-channel (N,3,1) arrays)
        float* o = out + c * (N_ * 3) + n * 3;
        o[0] = (float)(d0 * inv);
        o[1] = (float)(d1 * inv);
        o[2] = (float)(d2 * inv);
    }
}

extern "C" void kernel_launch(void* const* d_in, const int* in_sizes, int n_in,
                              void* d_out, int out_size, void* d_ws, size_t ws_size,
                              hipStream_t stream) {
    const float* W = (const float*)d_in[0];
    const float* g = (const float*)d_in[1];

    dim3 grid1(B_, N_);
    wls_partial<<<grid1, 256, 0, stream>>>(W, g, (float*)d_ws);
    wls_solve<<<N_ * NC_, 64, 0, stream>>>((const float*)d_ws, (float*)d_out);
}

// Round 4
// 118.137 us; speedup vs baseline: 1.1866x; 1.0007x over previous
//
#include <hip/hip_runtime.h>

#define N_   32
#define NC_  4
#define HW_  131072
#define REG_ 0.001
#define B_   32                       // h-chunks per n -> 1024 blocks (4/CU, 16 waves/CU)
#define CHUNK_ (HW_ / B_)             // 4096 h per block
#define ITERS_ (CHUNK_ / (256 * 4))   // 4 float4-groups per thread

// Kernel 1: partial moment sums.  grid (B_, N_), 256 threads.
// Each block covers all NC_=4 channels of its (n, h-chunk) so grid[] is read
// once.  8 moments per channel: k=0..4: sum w^2*y^k ; k=5..7: sum w^2*x*y^(k-5).
// Depth-2 register pipeline, fully unrolled (compile-time buffer indices).
__global__ __launch_bounds__(256) void wls_partial(const float* __restrict__ W,
                                                   const float* __restrict__ g,
                                                   float* __restrict__ ws) {
    const int n = blockIdx.y;
    const int b = blockIdx.x;
    const int t = threadIdx.x;
    const int hbase = b * CHUNK_;

    const float4* __restrict__ gvec = (const float4*)g + (n * HW_) / 2;
    const float4* __restrict__ wp0 = (const float4*)(W + (n * NC_ + 0) * HW_ + hbase) + t;
    const float4* __restrict__ wp1 = (const float4*)(W + (n * NC_ + 1) * HW_ + hbase) + t;
    const float4* __restrict__ wp2 = (const float4*)(W + (n * NC_ + 2) * HW_ + hbase) + t;
    const float4* __restrict__ wp3 = (const float4*)(W + (n * NC_ + 3) * HW_ + hbase) + t;

    float4 bg[2][2], bw[2][NC_];

    // prologue: load iter 0
    {
        const int h4 = hbase + t * 4;
        bg[0][0] = gvec[h4 >> 1];
        bg[0][1] = gvec[(h4 >> 1) + 1];
        bw[0][0] = wp0[0];
        bw[0][1] = wp1[0];
        bw[0][2] = wp2[0];
        bw[0][3] = wp3[0];
    }

    float acc[NC_][8];
#pragma unroll
    for (int c = 0; c < NC_; ++c)
#pragma unroll
        for (int k = 0; k < 8; ++k) acc[c][k] = 0.f;

#pragma unroll
    for (int i = 0; i < ITERS_; ++i) {
        const int cur = i & 1, nxt = cur ^ 1;   // compile-time (unrolled)
        if (i + 1 < ITERS_) {
            const int h4 = hbase + ((i + 1) * 256 + t) * 4;
            bg[nxt][0] = gvec[h4 >> 1];
            bg[nxt][1] = gvec[(h4 >> 1) + 1];
            bw[nxt][0] = wp0[(i + 1) * 256];
            bw[nxt][1] = wp1[(i + 1) * 256];
            bw[nxt][2] = wp2[(i + 1) * 256];
            bw[nxt][3] = wp3[(i + 1) * 256];
        }

        const float xs[4] = {bg[cur][0].x, bg[cur][0].z, bg[cur][1].x, bg[cur][1].z};
        const float ys[4] = {1.f - bg[cur][0].y, 1.f - bg[cur][0].w,
                             1.f - bg[cur][1].y, 1.f - bg[cur][1].w};
#pragma unroll
        for (int j = 0; j < 4; ++j) {
            const float x = xs[j], y = ys[j];
            const float y2 = y * y, y3 = y2 * y, y4 = y2 * y2;
#pragma unroll
            for (int c = 0; c < NC_; ++c) {
                const float w   = ((const float*)&bw[cur][c])[j];  // const idx (unrolled)
                const float w2  = w * w;
                const float w2x = w2 * x;
                acc[c][0] += w2;
                acc[c][1] = fmaf(w2, y,  acc[c][1]);
                acc[c][2] = fmaf(w2, y2, acc[c][2]);
                acc[c][3] = fmaf(w2, y3, acc[c][3]);
                acc[c][4] = fmaf(w2, y4, acc[c][4]);
                acc[c][5] += w2x;
                acc[c][6] = fmaf(w2x, y,  acc[c][6]);
                acc[c][7] = fmaf(w2x, y2, acc[c][7]);
            }
        }
    }

    // ---- wave (64-lane) shuffle reduction, then cross-wave via LDS ----
#pragma unroll
    for (int c = 0; c < NC_; ++c)
#pragma unroll
        for (int k = 0; k < 8; ++k) {
            float v = acc[c][k];
#pragma unroll
            for (int off = 32; off >= 1; off >>= 1) v += __shfl_down(v, off, 64);
            acc[c][k] = v;
        }

    __shared__ float lds[4 * 32];
    const int wave = t >> 6, lane = t & 63;
    if (lane == 0) {
#pragma unroll
        for (int c = 0; c < NC_; ++c)
#pragma unroll
            for (int k = 0; k < 8; ++k) lds[wave * 32 + c * 8 + k] = acc[c][k];
    }
    __syncthreads();
    if (t < 32)
        ws[(n * B_ + b) * 32 + t] =
            lds[t] + lds[32 + t] + lds[64 + t] + lds[96 + t];
}

// Kernel 2: 128 blocks (one per (n,c)) x 64 lanes.  Lanes 0..31 each load one
// partial's 8 moments (two float4), width-32 fp64 shuffle reduce, lane 0 does
// the 3x3 Cramer solve.
__global__ __launch_bounds__(64) void wls_solve(const float* __restrict__ ws,
                                                float* __restrict__ out) {
    const int n = blockIdx.x >> 2, c = blockIdx.x & 3;
    const int lane = threadIdx.x;

    double m[8] = {0, 0, 0, 0, 0, 0, 0, 0};
    if (lane < B_) {
        const float4* p = (const float4*)(ws + (n * B_ + lane) * 32 + c * 8);
        const float4 a = p[0], b4 = p[1];
        m[0] = a.x;  m[1] = a.y;  m[2] = a.z;  m[3] = a.w;
        m[4] = b4.x; m[5] = b4.y; m[6] = b4.z; m[7] = b4.w;
    }

#pragma unroll
    for (int off = 16; off >= 1; off >>= 1)
#pragma unroll
        for (int k = 0; k < 8; ++k) m[k] += __shfl_down(m[k], off, 32);

    if (lane == 0) {
        const double Z00 = m[4] + REG_, Z01 = m[3], Z02 = m[2];
        const double Z11 = m[2] + REG_, Z12 = m[1];
        const double Z22 = m[0] + REG_;
        const double X0 = m[7], X1 = m[6], X2 = m[5];

        const double c00 = Z11 * Z22 - Z12 * Z12;
        const double c01 = Z01 * Z22 - Z12 * Z02;
        const double c02 = Z01 * Z12 - Z11 * Z02;
        const double det = Z00 * c00 - Z01 * c01 + Z02 * c02;
        const double inv = 1.0 / det;

        const double d0 = X0 * c00
                        - Z01 * (X1 * Z22 - Z12 * X2)
                        + Z02 * (X1 * Z12 - Z11 * X2);
        const double d1 = Z00 * (X1 * Z22 - Z12 * X2)
                        - X0 * c01
                        + Z02 * (Z01 * X2 - X1 * Z02);
        const double d2 = Z00 * (Z11 * X2 - X1 * Z12)
                        - Z01 * (Z01 * X2 - X1 * Z02)
                        + X0 * c02;

        // out[c*96 + n*3 + p]  (tuple of per-channel (N,3,1) arrays)
        float* o = out + c * (N_ * 3) + n * 3;
        o[0] = (float)(d0 * inv);
        o[1] = (float)(d1 * inv);
        o[2] = (float)(d2 * inv);
    }
}

extern "C" void kernel_launch(void* const* d_in, const int* in_sizes, int n_in,
                              void* d_out, int out_size, void* d_ws, size_t ws_size,
                              hipStream_t stream) {
    const float* W = (const float*)d_in[0];
    const float* g = (const float*)d_in[1];

    dim3 grid1(B_, N_);
    wls_partial<<<grid1, 256, 0, stream>>>(W, g, (float*)d_ws);
    wls_solve<<<N_ * NC_, 64, 0, stream>>>((const float*)d_ws, (float*)d_out);
}